// Round 1
// baseline (773.133 us; speedup 1.0000x reference)
//
#include <hip/hip_runtime.h>
#include <hip/hip_bf16.h>

// FFB encoder, MI355X. Strategy: fused per-level [mid 3-mult split-bf16 MFMA +
// high 2-mult] with x resident in LDS (bf16 hi/lo), W pre-split into ws by a
// prep kernel. Wave grid 1x4 over h => each wave reads only its own W columns
// (dup=1 L2 traffic). Chain-critical sines via degree-9 poly (rev domain),
// high-branch sine via hardware v_sin_f32.

typedef __bf16 bf16_t;
typedef __attribute__((ext_vector_type(8))) __bf16 bf16x8;
typedef __attribute__((ext_vector_type(16))) float f32x16;

#define C56R 8.9126768f               // 56 / (2*pi)
#define INV7 0.14285714285714285f

// ws layout (bytes)
#define OFF_WMHI 0
#define OFF_WMLO 229376
#define OFF_WHHI 458752
#define OFF_CBM  688128
#define OFF_CBH  691712
#define OFF_AP   695296
#define OFF_C0   702464

// sin(2*pi*r) via quadrant reduction + odd degree-9 poly. |r| < ~60, abs err ~4e-6.
__device__ __forceinline__ float sin_rev(float r) {
  float fn = __builtin_rintf(r + r);
  float t  = __builtin_fmaf(fn, -0.5f, r);          // t in [-0.25, 0.25]
  int   k  = (int)fn;
  float t2 = t * t;
  float p  = __builtin_fmaf(t2, 42.058693f, -76.705859f);
  p = __builtin_fmaf(t2, p, 81.605249f);
  p = __builtin_fmaf(t2, p, -41.341702f);
  p = __builtin_fmaf(t2, p, 6.2831853f);
  float sres = t * p;
  sres = __uint_as_float(__float_as_uint(sres) ^ ((unsigned)k << 31));
  return sres;
}

__global__ void ffb_prep(const float* __restrict__ ffnA, const float* __restrict__ sigma,
                         const float* __restrict__ b0,
                         const float* __restrict__ Wm, const float* __restrict__ bm,
                         const float* __restrict__ Wh, const float* __restrict__ bh,
                         unsigned char* __restrict__ ws) {
  int i = blockIdx.x * 256 + threadIdx.x;
  bf16_t* wmhi = (bf16_t*)(ws + OFF_WMHI);
  bf16_t* wmlo = (bf16_t*)(ws + OFF_WMLO);
  bf16_t* whhi = (bf16_t*)(ws + OFF_WHHI);
  float*  cbm  = (float*)(ws + OFF_CBM);
  float*  cbh  = (float*)(ws + OFF_CBH);
  float*  ap   = (float*)(ws + OFF_AP);
  float*  c0   = (float*)(ws + OFF_C0);
  if (i < 7 * 128 * 128) {
    float w = Wm[i];
    bf16_t h = (bf16_t)w;
    wmhi[i] = h;
    wmlo[i] = (bf16_t)(w - (float)h);
    whhi[i] = (bf16_t)Wh[i];
  }
  if (i < 896)  { cbm[i] = C56R * bm[i]; cbh[i] = C56R * bh[i]; }
  if (i < 1792) { ap[i] = ffnA[i] * sigma[i >> 8]; }
  if (i < 128)  { c0[i] = C56R * b0[i]; }
}

__launch_bounds__(256, 2)
__global__ void ffb_main(const float* __restrict__ pos,
                         const float* __restrict__ gfeat,
                         const float* __restrict__ W0,
                         const unsigned char* __restrict__ ws,
                         float* __restrict__ out) {
  // 272B row stride: 16B-aligned ds_read_b128, balanced 8-deep bank access.
  __shared__ __align__(16) bf16_t Xhi[128 * 136];
  __shared__ __align__(16) bf16_t Xlo[128 * 136];

  const int tid    = threadIdx.x;
  const int base_n = blockIdx.x << 7;
  const int w   = tid >> 6;
  const int L   = tid & 63;
  const int s   = L & 31;       // mfma lane-col (and A-frag m)
  const int h5  = L >> 5;       // k-half selector
  const int col = (w << 5) + s; // this lane's h column, constant all kernel

  const bf16_t* __restrict__ WMHI = (const bf16_t*)(ws + OFF_WMHI);
  const bf16_t* __restrict__ WMLO = (const bf16_t*)(ws + OFF_WMLO);
  const bf16_t* __restrict__ WHHI = (const bf16_t*)(ws + OFF_WHHI);
  const float*  __restrict__ CBM  = (const float*)(ws + OFF_CBM);
  const float*  __restrict__ CBH  = (const float*)(ws + OFF_CBH);
  const float*  __restrict__ AP   = (const float*)(ws + OFF_AP);
  const float*  __restrict__ C0   = (const float*)(ws + OFF_C0);

  // pos01 -> out[:, 0:3]
  if (tid < 128) {
    int n = base_n + tid;
    float p0 = pos[n*3+0], p1 = pos[n*3+1], p2 = pos[n*3+2];
    out[n*131+0] = (p0 + 1.f) * 0.5f;
    out[n*131+1] = (p1 + 1.f) * 0.5f;
    out[n*131+2] = (p2 + 1.f) * 0.5f;
  }

  // layer 0: x0 = sin(56*(pos @ W0^T + b0)) -> LDS hi/lo. 2 threads per row.
  {
    int nl = tid >> 1;
    int n  = base_n + nl;
    int hstart = (tid & 1) << 6;
    float p0 = pos[n*3+0], p1 = pos[n*3+1], p2 = pos[n*3+2];
    #pragma unroll 8
    for (int h = hstart; h < hstart + 64; h += 2) {
      float d0 = p0*W0[h*3+0] + p1*W0[h*3+1] + p2*W0[h*3+2];
      float d1 = p0*W0[h*3+3] + p1*W0[h*3+4] + p2*W0[h*3+5];
      float x0 = sin_rev(__builtin_fmaf(d0, C56R, C0[h]));
      float x1 = sin_rev(__builtin_fmaf(d1, C56R, C0[h+1]));
      bf16_t hi0 = (bf16_t)x0, hi1 = (bf16_t)x1;
      Xhi[nl*136 + h]     = hi0;
      Xhi[nl*136 + h + 1] = hi1;
      Xlo[nl*136 + h]     = (bf16_t)(x0 - (float)hi0);
      Xlo[nl*136 + h + 1] = (bf16_t)(x1 - (float)hi1);
    }
  }
  __syncthreads();

  f32x16 buf[4];
  #pragma unroll
  for (int mt = 0; mt < 4; ++mt)
    #pragma unroll
    for (int r = 0; r < 16; ++r) buf[mt][r] = 0.f;

  for (int it = 0; it < 8; ++it) {
    const bool do_mid  = (it < 7);   // mid_it reads x_it
    const bool do_high = (it > 0);   // high_{it-1} reads x_it
    const int  itm1    = it ? it - 1 : 0;

    f32x16 accm[4], acch[4];
    #pragma unroll
    for (int mt = 0; mt < 4; ++mt)
      #pragma unroll
      for (int r = 0; r < 16; ++r) { accm[mt][r] = 0.f; acch[mt][r] = 0.f; }

    const bf16_t* wmh = WMHI + (it << 14)   + (col << 7);
    const bf16_t* wml = WMLO + (it << 14)   + (col << 7);
    const bf16_t* whh = WHHI + (itm1 << 14) + (col << 7);

    for (int kc = 0; kc < 8; ++kc) {
      const int kof = (kc << 4) + (h5 << 3);
      bf16x8 Bmh, Bml, Bhh;
      if (do_mid) {
        Bmh = *(const bf16x8*)(wmh + kof);   // W_mid[it][col][k..k+7] hi
        Bml = *(const bf16x8*)(wml + kof);
      }
      if (do_high) {
        Bhh = *(const bf16x8*)(whh + kof);
      }
      #pragma unroll
      for (int mt = 0; mt < 4; ++mt) {
        const int row = (mt << 5) + s;
        bf16x8 Ahi = *(const bf16x8*)(&Xhi[row*136 + kof]);
        bf16x8 Alo = *(const bf16x8*)(&Xlo[row*136 + kof]);
        if (do_mid) {
          accm[mt] = __builtin_amdgcn_mfma_f32_32x32x16_bf16(Ahi, Bmh, accm[mt], 0, 0, 0);
          accm[mt] = __builtin_amdgcn_mfma_f32_32x32x16_bf16(Ahi, Bml, accm[mt], 0, 0, 0);
          accm[mt] = __builtin_amdgcn_mfma_f32_32x32x16_bf16(Alo, Bmh, accm[mt], 0, 0, 0);
        }
        if (do_high) {
          acch[mt] = __builtin_amdgcn_mfma_f32_32x32x16_bf16(Ahi, Bhh, acch[mt], 0, 0, 0);
          acch[mt] = __builtin_amdgcn_mfma_f32_32x32x16_bf16(Alo, Bhh, acch[mt], 0, 0, 0);
        }
      }
    }

    // high branch epilogue (registers only): buf += sin(56*(Yh + bh))
    if (do_high) {
      const float cbh_l = CBH[(itm1 << 7) + col];
      #pragma unroll
      for (int mt = 0; mt < 4; ++mt)
        #pragma unroll
        for (int r = 0; r < 16; ++r)
          buf[mt][r] += __builtin_amdgcn_sinf(__builtin_fmaf(acch[mt][r], C56R, cbh_l));
    }

    __syncthreads();  // all waves done reading X_cur

    // mid epilogue: x_next = grid + sin(56*(Ym + bm)) -> LDS hi/lo
    if (do_mid) {
      const float cbm_l = CBM[(it << 7) + col];
      const float ap0 = AP[(it << 8) + col];
      const float ap1 = AP[(it << 8) + 128 + col];
      const float* gp = gfeat + 3 + (it << 1);
      #pragma unroll
      for (int mt = 0; mt < 4; ++mt) {
        #pragma unroll
        for (int r = 0; r < 16; ++r) {
          const int rowl = (mt << 5) + (r & 3) + ((r >> 2) << 3) + (h5 << 2);
          const int n = base_n + rowl;
          float gx0 = gp[n*17];
          float gx1 = gp[n*17 + 1];
          float grev = __builtin_fmaf(gx1, ap1, gx0 * ap0);
          float xv = sin_rev(grev) + sin_rev(__builtin_fmaf(accm[mt][r], C56R, cbm_l));
          bf16_t hi = (bf16_t)xv;
          Xhi[rowl*136 + col] = hi;
          Xlo[rowl*136 + col] = (bf16_t)(xv - (float)hi);
        }
      }
      __syncthreads();  // X_next ready
    }
  }

  // out[:, 3:131] = buf / 7
  #pragma unroll
  for (int mt = 0; mt < 4; ++mt) {
    #pragma unroll
    for (int r = 0; r < 16; ++r) {
      const int rowl = (mt << 5) + (r & 3) + ((r >> 2) << 3) + (h5 << 2);
      out[(base_n + rowl)*131 + 3 + col] = buf[mt][r] * INV7;
    }
  }
}

extern "C" void kernel_launch(void* const* d_in, const int* in_sizes, int n_in,
                              void* d_out, int out_size, void* d_ws, size_t ws_size,
                              hipStream_t stream) {
  (void)in_sizes; (void)n_in; (void)out_size; (void)ws_size;
  const float* pos   = (const float*)d_in[0];
  const float* gfeat = (const float*)d_in[1];
  const float* ffnA  = (const float*)d_in[2];
  const float* sigma = (const float*)d_in[3];
  const float* W0    = (const float*)d_in[4];
  const float* b0    = (const float*)d_in[5];
  const float* Wm    = (const float*)d_in[6];
  const float* bm    = (const float*)d_in[7];
  const float* Wh    = (const float*)d_in[8];
  const float* bh    = (const float*)d_in[9];
  float* out = (float*)d_out;
  unsigned char* ws = (unsigned char*)d_ws;

  hipLaunchKernelGGL(ffb_prep, dim3(448), dim3(256), 0, stream,
                     ffnA, sigma, b0, Wm, bm, Wh, bh, ws);
  hipLaunchKernelGGL(ffb_main, dim3(1024), dim3(256), 0, stream,
                     pos, gfeat, W0, ws, out);
}

// Round 2
// 315.024 us; speedup vs baseline: 2.4542x; 2.4542x over previous
//
#include <hip/hip_runtime.h>
#include <hip/hip_bf16.h>

// FFB encoder, MI355X. Round 2: fused per-level [high 2-mult then mid 3-mult]
// split-bf16 MFMA with x resident in LDS (bf16 hi/lo). Sequential accumulator
// usage (one 64-reg MFMA acc live at a time + 64-reg buf) to avoid scratch
// spills. Output staged in LDS and written flat-coalesced. gfeat staged in LDS.

typedef __bf16 bf16_t;
typedef __attribute__((ext_vector_type(8))) __bf16 bf16x8;
typedef __attribute__((ext_vector_type(16))) float f32x16;

#define C56R 8.9126768f               // 56 / (2*pi)
#define INV7 0.14285714285714285f

// ws layout (bytes)
#define OFF_WMHI 0
#define OFF_WMLO 229376
#define OFF_WHHI 458752
#define OFF_CBM  688128
#define OFF_CBH  691712
#define OFF_AP   695296
#define OFF_C0   702464

// sin(2*pi*r) via quadrant reduction + odd degree-9 poly. abs err ~4e-6.
__device__ __forceinline__ float sin_rev(float r) {
  float fn = __builtin_rintf(r + r);
  float t  = __builtin_fmaf(fn, -0.5f, r);          // t in [-0.25, 0.25]
  int   k  = (int)fn;
  float t2 = t * t;
  float p  = __builtin_fmaf(t2, 42.058693f, -76.705859f);
  p = __builtin_fmaf(t2, p, 81.605249f);
  p = __builtin_fmaf(t2, p, -41.341702f);
  p = __builtin_fmaf(t2, p, 6.2831853f);
  float sres = t * p;
  sres = __uint_as_float(__float_as_uint(sres) ^ ((unsigned)k << 31));
  return sres;
}

__global__ void ffb_prep(const float* __restrict__ ffnA, const float* __restrict__ sigma,
                         const float* __restrict__ b0,
                         const float* __restrict__ Wm, const float* __restrict__ bm,
                         const float* __restrict__ Wh, const float* __restrict__ bh,
                         unsigned char* __restrict__ ws) {
  int i = blockIdx.x * 256 + threadIdx.x;
  bf16_t* wmhi = (bf16_t*)(ws + OFF_WMHI);
  bf16_t* wmlo = (bf16_t*)(ws + OFF_WMLO);
  bf16_t* whhi = (bf16_t*)(ws + OFF_WHHI);
  float*  cbm  = (float*)(ws + OFF_CBM);
  float*  cbh  = (float*)(ws + OFF_CBH);
  float*  ap   = (float*)(ws + OFF_AP);
  float*  c0   = (float*)(ws + OFF_C0);
  if (i < 7 * 128 * 128) {
    float w = Wm[i];
    bf16_t h = (bf16_t)w;
    wmhi[i] = h;
    wmlo[i] = (bf16_t)(w - (float)h);
    whhi[i] = (bf16_t)Wh[i];
  }
  if (i < 896)  { cbm[i] = C56R * bm[i]; cbh[i] = C56R * bh[i]; }
  if (i < 1792) { ap[i] = ffnA[i] * sigma[i >> 8]; }
  if (i < 128)  { c0[i] = C56R * b0[i]; }
}

__launch_bounds__(256, 2)
__global__ void ffb_main(const float* __restrict__ pos,
                         const float* __restrict__ gfeat,
                         const float* __restrict__ W0,
                         const unsigned char* __restrict__ ws,
                         float* __restrict__ out) {
  // smem carve: Xhi [128][136] bf16, Xlo [128][136] bf16, GF [128][14] f32.
  // Out staging (67072 B) overlays Xhi+Xlo (69632 B) after the final barrier.
  __shared__ __align__(16) unsigned char smem[69632 + 128 * 14 * 4];
  bf16_t* Xhi = (bf16_t*)smem;
  bf16_t* Xlo = (bf16_t*)(smem + 34816);
  float*  GF  = (float*)(smem + 69632);
  float*  OST = (float*)smem;

  const int tid    = threadIdx.x;
  const int base_n = blockIdx.x << 7;
  const int w   = tid >> 6;
  const int L   = tid & 63;
  const int s   = L & 31;       // mfma lane-col (and A-frag m)
  const int h5  = L >> 5;       // k-half selector
  const int col = (w << 5) + s; // this lane's h column, constant all kernel

  const bf16_t* __restrict__ WMHI = (const bf16_t*)(ws + OFF_WMHI);
  const bf16_t* __restrict__ WMLO = (const bf16_t*)(ws + OFF_WMLO);
  const bf16_t* __restrict__ WHHI = (const bf16_t*)(ws + OFF_WHHI);
  const float*  __restrict__ CBM  = (const float*)(ws + OFF_CBM);
  const float*  __restrict__ CBH  = (const float*)(ws + OFF_CBH);
  const float*  __restrict__ AP   = (const float*)(ws + OFF_AP);
  const float*  __restrict__ C0   = (const float*)(ws + OFF_C0);

  // stage gfeat cols 3..16 -> GF[128][14] (coalesced)
  for (int i = tid; i < 128 * 14; i += 256) {
    int n = i / 14, l = i - n * 14;
    GF[i] = gfeat[(size_t)(base_n + n) * 17 + 3 + l];
  }

  // layer 0: x0 = sin(56*(pos @ W0^T + b0)) -> LDS hi/lo. 2 threads per row.
  {
    int nl = tid >> 1;
    int n  = base_n + nl;
    int hstart = (tid & 1) << 6;
    float p0 = pos[n*3+0], p1 = pos[n*3+1], p2 = pos[n*3+2];
    #pragma unroll 8
    for (int h = hstart; h < hstart + 64; h += 2) {
      float d0 = p0*W0[h*3+0] + p1*W0[h*3+1] + p2*W0[h*3+2];
      float d1 = p0*W0[h*3+3] + p1*W0[h*3+4] + p2*W0[h*3+5];
      float x0 = sin_rev(__builtin_fmaf(d0, C56R, C0[h]));
      float x1 = sin_rev(__builtin_fmaf(d1, C56R, C0[h+1]));
      bf16_t hi0 = (bf16_t)x0, hi1 = (bf16_t)x1;
      Xhi[nl*136 + h]     = hi0;
      Xhi[nl*136 + h + 1] = hi1;
      Xlo[nl*136 + h]     = (bf16_t)(x0 - (float)hi0);
      Xlo[nl*136 + h + 1] = (bf16_t)(x1 - (float)hi1);
    }
  }
  __syncthreads();

  f32x16 buf[4];
  #pragma unroll
  for (int mt = 0; mt < 4; ++mt)
    #pragma unroll
    for (int r = 0; r < 16; ++r) buf[mt][r] = 0.f;

  for (int it = 0; it < 8; ++it) {
    // ---- high pass: level it-1, consumes x_it (current LDS contents) ----
    if (it > 0) {
      f32x16 acc[4];
      #pragma unroll
      for (int mt = 0; mt < 4; ++mt)
        #pragma unroll
        for (int r = 0; r < 16; ++r) acc[mt][r] = 0.f;
      const bf16_t* whh = WHHI + ((it - 1) << 14) + (col << 7);
      #pragma unroll 2
      for (int kc = 0; kc < 8; ++kc) {
        const int kof = (kc << 4) + (h5 << 3);
        bf16x8 Bhh = *(const bf16x8*)(whh + kof);
        #pragma unroll
        for (int mt = 0; mt < 4; ++mt) {
          const int row = (mt << 5) + s;
          bf16x8 Ahi = *(const bf16x8*)(&Xhi[row*136 + kof]);
          bf16x8 Alo = *(const bf16x8*)(&Xlo[row*136 + kof]);
          acc[mt] = __builtin_amdgcn_mfma_f32_32x32x16_bf16(Ahi, Bhh, acc[mt], 0, 0, 0);
          acc[mt] = __builtin_amdgcn_mfma_f32_32x32x16_bf16(Alo, Bhh, acc[mt], 0, 0, 0);
        }
      }
      const float cbh_l = CBH[((it - 1) << 7) + col];
      #pragma unroll
      for (int mt = 0; mt < 4; ++mt)
        #pragma unroll
        for (int r = 0; r < 16; ++r)
          buf[mt][r] += __builtin_amdgcn_sinf(__builtin_fmaf(acc[mt][r], C56R, cbh_l));
    }

    // ---- mid pass: level it, consumes x_it, produces x_{it+1} ----
    if (it < 7) {
      f32x16 acc[4];
      #pragma unroll
      for (int mt = 0; mt < 4; ++mt)
        #pragma unroll
        for (int r = 0; r < 16; ++r) acc[mt][r] = 0.f;
      const bf16_t* wmh = WMHI + (it << 14) + (col << 7);
      const bf16_t* wml = WMLO + (it << 14) + (col << 7);
      #pragma unroll 2
      for (int kc = 0; kc < 8; ++kc) {
        const int kof = (kc << 4) + (h5 << 3);
        bf16x8 Bmh = *(const bf16x8*)(wmh + kof);
        bf16x8 Bml = *(const bf16x8*)(wml + kof);
        #pragma unroll
        for (int mt = 0; mt < 4; ++mt) {
          const int row = (mt << 5) + s;
          bf16x8 Ahi = *(const bf16x8*)(&Xhi[row*136 + kof]);
          bf16x8 Alo = *(const bf16x8*)(&Xlo[row*136 + kof]);
          acc[mt] = __builtin_amdgcn_mfma_f32_32x32x16_bf16(Ahi, Bmh, acc[mt], 0, 0, 0);
          acc[mt] = __builtin_amdgcn_mfma_f32_32x32x16_bf16(Ahi, Bml, acc[mt], 0, 0, 0);
          acc[mt] = __builtin_amdgcn_mfma_f32_32x32x16_bf16(Alo, Bmh, acc[mt], 0, 0, 0);
        }
      }
      __syncthreads();  // all waves done reading x_it
      const float cbm_l = CBM[(it << 7) + col];
      const float ap0 = AP[(it << 8) + col];
      const float ap1 = AP[(it << 8) + 128 + col];
      #pragma unroll
      for (int mt = 0; mt < 4; ++mt) {
        #pragma unroll
        for (int r = 0; r < 16; ++r) {
          const int rowl = (mt << 5) + (r & 3) + ((r >> 2) << 3) + (h5 << 2);
          float gx0 = GF[rowl * 14 + (it << 1)];
          float gx1 = GF[rowl * 14 + (it << 1) + 1];
          float grev = __builtin_fmaf(gx1, ap1, gx0 * ap0);
          float xv = sin_rev(grev) + sin_rev(__builtin_fmaf(acc[mt][r], C56R, cbm_l));
          bf16_t hi = (bf16_t)xv;
          Xhi[rowl*136 + col] = hi;
          Xlo[rowl*136 + col] = (bf16_t)(xv - (float)hi);
        }
      }
      __syncthreads();  // x_{it+1} ready
    }
  }

  // ---- epilogue: stage [128][131] out rows in LDS, then flat coalesced copy
  __syncthreads();  // everyone done reading Xhi/Xlo (it=7 high pass)
  #pragma unroll
  for (int mt = 0; mt < 4; ++mt) {
    #pragma unroll
    for (int r = 0; r < 16; ++r) {
      const int rowl = (mt << 5) + (r & 3) + ((r >> 2) << 3) + (h5 << 2);
      OST[rowl * 131 + 3 + col] = buf[mt][r] * INV7;
    }
  }
  if (tid < 128) {
    int n = base_n + tid;
    OST[tid * 131 + 0] = (pos[n*3+0] + 1.f) * 0.5f;
    OST[tid * 131 + 1] = (pos[n*3+1] + 1.f) * 0.5f;
    OST[tid * 131 + 2] = (pos[n*3+2] + 1.f) * 0.5f;
  }
  __syncthreads();
  {
    float* outp = out + (size_t)base_n * 131;
    for (int i = tid; i < 128 * 131; i += 256) outp[i] = OST[i];
  }
}

extern "C" void kernel_launch(void* const* d_in, const int* in_sizes, int n_in,
                              void* d_out, int out_size, void* d_ws, size_t ws_size,
                              hipStream_t stream) {
  (void)in_sizes; (void)n_in; (void)out_size; (void)ws_size;
  const float* pos   = (const float*)d_in[0];
  const float* gfeat = (const float*)d_in[1];
  const float* ffnA  = (const float*)d_in[2];
  const float* sigma = (const float*)d_in[3];
  const float* W0    = (const float*)d_in[4];
  const float* b0    = (const float*)d_in[5];
  const float* Wm    = (const float*)d_in[6];
  const float* bm    = (const float*)d_in[7];
  const float* Wh    = (const float*)d_in[8];
  const float* bh    = (const float*)d_in[9];
  float* out = (float*)d_out;
  unsigned char* ws = (unsigned char*)d_ws;

  hipLaunchKernelGGL(ffb_prep, dim3(448), dim3(256), 0, stream,
                     ffnA, sigma, b0, Wm, bm, Wh, bh, ws);
  hipLaunchKernelGGL(ffb_main, dim3(1024), dim3(256), 0, stream,
                     pos, gfeat, W0, ws, out);
}

// Round 3
// 303.405 us; speedup vs baseline: 2.5482x; 1.0383x over previous
//
#include <hip/hip_runtime.h>
#include <hip/hip_bf16.h>

// FFB encoder, MI355X. Round 3: 64-row WGs (4 WG/CU), hw v_sin everywhere
// (grid branch gets exact v_fract pre-reduction), high pass 1-mult bf16-hi,
// mid pass 3-mult split-bf16. x resident in LDS hi/lo; sequential acc usage.

typedef __bf16 bf16_t;
typedef __attribute__((ext_vector_type(8))) __bf16 bf16x8;
typedef __attribute__((ext_vector_type(4))) float f32x4;
typedef __attribute__((ext_vector_type(16))) float f32x16;

#define C56R 8.9126768f               // 56 / (2*pi)
#define INV7 0.14285714285714285f

// ws layout (bytes)
#define OFF_WMHI 0
#define OFF_WMLO 229376
#define OFF_WHHI 458752
#define OFF_CBM  688128
#define OFF_CBH  691712
#define OFF_AP   695296
#define OFF_C0   702464

__global__ void ffb_prep(const float* __restrict__ ffnA, const float* __restrict__ sigma,
                         const float* __restrict__ b0,
                         const float* __restrict__ Wm, const float* __restrict__ bm,
                         const float* __restrict__ Wh, const float* __restrict__ bh,
                         unsigned char* __restrict__ ws) {
  int i = blockIdx.x * 256 + threadIdx.x;
  bf16_t* wmhi = (bf16_t*)(ws + OFF_WMHI);
  bf16_t* wmlo = (bf16_t*)(ws + OFF_WMLO);
  bf16_t* whhi = (bf16_t*)(ws + OFF_WHHI);
  float*  cbm  = (float*)(ws + OFF_CBM);
  float*  cbh  = (float*)(ws + OFF_CBH);
  float*  ap   = (float*)(ws + OFF_AP);
  float*  c0   = (float*)(ws + OFF_C0);
  if (i < 7 * 128 * 128) {
    float w = Wm[i];
    bf16_t h = (bf16_t)w;
    wmhi[i] = h;
    wmlo[i] = (bf16_t)(w - (float)h);
    whhi[i] = (bf16_t)Wh[i];
  }
  if (i < 896)  { cbm[i] = C56R * bm[i]; cbh[i] = C56R * bh[i]; }
  if (i < 1792) { ap[i] = ffnA[i] * sigma[i >> 8]; }
  if (i < 128)  { c0[i] = C56R * b0[i]; }
}

__launch_bounds__(256, 4)
__global__ void ffb_main(const float* __restrict__ pos,
                         const float* __restrict__ gfeat,
                         const float* __restrict__ W0,
                         const unsigned char* __restrict__ ws,
                         float* __restrict__ out) {
  // smem: Xhi bf16[64][136] (17408 B) | Xlo (17408 B) | GF f32[64][14] (3584 B)
  // OST f32[64][131] (33536 B) overlays Xhi/Xlo after the final barrier.
  __shared__ __align__(16) unsigned char smem[38400];
  bf16_t* Xhi = (bf16_t*)smem;
  bf16_t* Xlo = (bf16_t*)(smem + 17408);
  float*  GF  = (float*)(smem + 34816);
  float*  OST = (float*)smem;

  const int tid    = threadIdx.x;
  const int base_n = blockIdx.x << 6;
  const int w   = tid >> 6;
  const int L   = tid & 63;
  const int s   = L & 31;       // mfma lane-col (and A-frag m)
  const int h5  = L >> 5;       // k-half selector
  const int col = (w << 5) + s; // this lane's h column, constant all kernel

  const bf16_t* __restrict__ WMHI = (const bf16_t*)(ws + OFF_WMHI);
  const bf16_t* __restrict__ WMLO = (const bf16_t*)(ws + OFF_WMLO);
  const bf16_t* __restrict__ WHHI = (const bf16_t*)(ws + OFF_WHHI);
  const float*  __restrict__ CBM  = (const float*)(ws + OFF_CBM);
  const float*  __restrict__ CBH  = (const float*)(ws + OFF_CBH);
  const float*  __restrict__ AP   = (const float*)(ws + OFF_AP);
  const float*  __restrict__ C0   = (const float*)(ws + OFF_C0);

  // stage gfeat cols 3..16 -> GF[64][14] (coalesced)
  for (int i = tid; i < 64 * 14; i += 256) {
    int n = i / 14, l = i - n * 14;
    GF[i] = gfeat[(size_t)(base_n + n) * 17 + 3 + l];
  }

  // layer 0: x0 = sin(56*(pos @ W0^T + b0)) -> LDS hi/lo. 4 threads per row.
  {
    int rl = tid >> 2;
    int n  = base_n + rl;
    int hstart = (tid & 3) << 5;
    float p0 = pos[n*3+0], p1 = pos[n*3+1], p2 = pos[n*3+2];
    #pragma unroll 8
    for (int h = hstart; h < hstart + 32; ++h) {
      float d = p0*W0[h*3+0] + p1*W0[h*3+1] + p2*W0[h*3+2];
      float x0 = __builtin_amdgcn_sinf(__builtin_fmaf(d, C56R, C0[h]));
      bf16_t hi = (bf16_t)x0;
      Xhi[rl*136 + h] = hi;
      Xlo[rl*136 + h] = (bf16_t)(x0 - (float)hi);
    }
  }
  __syncthreads();

  f32x16 buf[2];
  #pragma unroll
  for (int mt = 0; mt < 2; ++mt)
    #pragma unroll
    for (int r = 0; r < 16; ++r) buf[mt][r] = 0.f;

  for (int it = 0; it < 8; ++it) {
    // ---- high pass: level it-1, 1-mult (bf16-hi only), consumes x_it ----
    if (it > 0) {
      f32x16 acc[2];
      #pragma unroll
      for (int mt = 0; mt < 2; ++mt)
        #pragma unroll
        for (int r = 0; r < 16; ++r) acc[mt][r] = 0.f;
      const bf16_t* whh = WHHI + ((it - 1) << 14) + (col << 7);
      #pragma unroll 4
      for (int kc = 0; kc < 8; ++kc) {
        const int kof = (kc << 4) + (h5 << 3);
        bf16x8 Bhh = *(const bf16x8*)(whh + kof);
        #pragma unroll
        for (int mt = 0; mt < 2; ++mt) {
          bf16x8 Ahi = *(const bf16x8*)(&Xhi[((mt << 5) + s)*136 + kof]);
          acc[mt] = __builtin_amdgcn_mfma_f32_32x32x16_bf16(Ahi, Bhh, acc[mt], 0, 0, 0);
        }
      }
      const float cbh_l = CBH[((it - 1) << 7) + col];
      #pragma unroll
      for (int mt = 0; mt < 2; ++mt)
        #pragma unroll
        for (int r = 0; r < 16; ++r)
          buf[mt][r] += __builtin_amdgcn_sinf(__builtin_fmaf(acc[mt][r], C56R, cbh_l));
    }

    // ---- mid pass: level it, 3-mult split, consumes x_it, produces x_{it+1}
    if (it < 7) {
      f32x16 acc[2];
      #pragma unroll
      for (int mt = 0; mt < 2; ++mt)
        #pragma unroll
        for (int r = 0; r < 16; ++r) acc[mt][r] = 0.f;
      const bf16_t* wmh = WMHI + (it << 14) + (col << 7);
      const bf16_t* wml = WMLO + (it << 14) + (col << 7);
      #pragma unroll 2
      for (int kc = 0; kc < 8; ++kc) {
        const int kof = (kc << 4) + (h5 << 3);
        bf16x8 Bmh = *(const bf16x8*)(wmh + kof);
        bf16x8 Bml = *(const bf16x8*)(wml + kof);
        #pragma unroll
        for (int mt = 0; mt < 2; ++mt) {
          bf16x8 Ahi = *(const bf16x8*)(&Xhi[((mt << 5) + s)*136 + kof]);
          bf16x8 Alo = *(const bf16x8*)(&Xlo[((mt << 5) + s)*136 + kof]);
          acc[mt] = __builtin_amdgcn_mfma_f32_32x32x16_bf16(Ahi, Bmh, acc[mt], 0, 0, 0);
          acc[mt] = __builtin_amdgcn_mfma_f32_32x32x16_bf16(Ahi, Bml, acc[mt], 0, 0, 0);
          acc[mt] = __builtin_amdgcn_mfma_f32_32x32x16_bf16(Alo, Bmh, acc[mt], 0, 0, 0);
        }
      }
      __syncthreads();  // all waves done reading x_it (high+mid)
      const float cbm_l = CBM[(it << 7) + col];
      const float ap0 = AP[(it << 8) + col];
      const float ap1 = AP[(it << 8) + 128 + col];
      #pragma unroll
      for (int mt = 0; mt < 2; ++mt) {
        #pragma unroll
        for (int r = 0; r < 16; ++r) {
          const int rowl = (mt << 5) + (r & 3) + ((r >> 2) << 3) + (h5 << 2);
          float gx0 = GF[rowl * 14 + (it << 1)];
          float gx1 = GF[rowl * 14 + (it << 1) + 1];
          float grev = __builtin_fmaf(gx1, ap1, gx0 * ap0);
          // exact phase reduction, then hw sin (grid args can reach ~1e2 rev)
          float sg = __builtin_amdgcn_sinf(__builtin_amdgcn_fractf(grev));
          float sm = __builtin_amdgcn_sinf(__builtin_fmaf(acc[mt][r], C56R, cbm_l));
          float xv = sg + sm;
          bf16_t hi = (bf16_t)xv;
          Xhi[rowl*136 + col] = hi;
          Xlo[rowl*136 + col] = (bf16_t)(xv - (float)hi);
        }
      }
      __syncthreads();  // x_{it+1} ready
    }
  }

  // ---- epilogue: stage [64][131] rows in LDS, then float4 coalesced copy
  __syncthreads();  // everyone done reading Xhi (it=7 high pass)
  #pragma unroll
  for (int mt = 0; mt < 2; ++mt) {
    #pragma unroll
    for (int r = 0; r < 16; ++r) {
      const int rowl = (mt << 5) + (r & 3) + ((r >> 2) << 3) + (h5 << 2);
      OST[rowl * 131 + 3 + col] = buf[mt][r] * INV7;
    }
  }
  if (tid < 64) {
    int n = base_n + tid;
    OST[tid * 131 + 0] = (pos[n*3+0] + 1.f) * 0.5f;
    OST[tid * 131 + 1] = (pos[n*3+1] + 1.f) * 0.5f;
    OST[tid * 131 + 2] = (pos[n*3+2] + 1.f) * 0.5f;
  }
  __syncthreads();
  {
    f32x4* outp = (f32x4*)(out + (size_t)base_n * 131);
    const f32x4* ostv = (const f32x4*)OST;
    for (int i = tid; i < 64 * 131 / 4; i += 256) outp[i] = ostv[i];
  }
}

extern "C" void kernel_launch(void* const* d_in, const int* in_sizes, int n_in,
                              void* d_out, int out_size, void* d_ws, size_t ws_size,
                              hipStream_t stream) {
  (void)in_sizes; (void)n_in; (void)out_size; (void)ws_size;
  const float* pos   = (const float*)d_in[0];
  const float* gfeat = (const float*)d_in[1];
  const float* ffnA  = (const float*)d_in[2];
  const float* sigma = (const float*)d_in[3];
  const float* W0    = (const float*)d_in[4];
  const float* b0    = (const float*)d_in[5];
  const float* Wm    = (const float*)d_in[6];
  const float* bm    = (const float*)d_in[7];
  const float* Wh    = (const float*)d_in[8];
  const float* bh    = (const float*)d_in[9];
  float* out = (float*)d_out;
  unsigned char* ws = (unsigned char*)d_ws;

  hipLaunchKernelGGL(ffb_prep, dim3(448), dim3(256), 0, stream,
                     ffnA, sigma, b0, Wm, bm, Wh, bh, ws);
  hipLaunchKernelGGL(ffb_main, dim3(2048), dim3(256), 0, stream,
                     pos, gfeat, W0, ws, out);
}